// Round 9
// baseline (394.474 us; speedup 1.0000x reference)
//
#include <hip/hip_runtime.h>
#include <hip/hip_bf16.h>

#define DM   1024
#define DI   64
#define H_   16
#define B_   2
#define S_   2048
#define NTOK 4096   // B*S

typedef unsigned short u16;
typedef unsigned int u32;
typedef __attribute__((ext_vector_type(8))) short s16x8;
typedef __attribute__((ext_vector_type(4))) float f32x4;
typedef __attribute__((ext_vector_type(4))) unsigned int u32x4;
typedef __attribute__((ext_vector_type(4))) unsigned short u16x4;

#define AS1 __attribute__((address_space(1)))
#define AS3 __attribute__((address_space(3)))

static __device__ __forceinline__ u16 f2bf(float f) {
  unsigned int u = __builtin_bit_cast(unsigned int, f);
  unsigned int r = (u + 0x7fffu + ((u >> 16) & 1u)) >> 16;
  return (u16)r;
}

static __device__ __forceinline__ void gload_lds16(const u16* g, u16* l) {
  __builtin_amdgcn_global_load_lds((const AS1 u32*)(const void*)g,
                                   (AS3 u32*)(void*)l, 16, 0, 0);
}

// LDS-only barrier: drain this wave's DS ops, then s_barrier. Global NT stores
// and prefetch loads stay in flight (no vmcnt(0) drain like __syncthreads).
static __device__ __forceinline__ void lds_barrier() {
  asm volatile("s_waitcnt lgkmcnt(0)\n\ts_barrier" ::: "memory");
}

// ---------------- small prep kernels ----------------

__global__ void k_cvt_x(const float* __restrict__ in, u16* __restrict__ out) {
  int i = (blockIdx.x * 256 + threadIdx.x) * 4;
  float4 v = *(const float4*)&in[i];
  u16x4 o;
  o[0] = f2bf(v.x); o[1] = f2bf(v.y); o[2] = f2bf(v.z); o[3] = f2bf(v.w);
  *(u16x4*)&out[i] = o;
}

__global__ void k_small(const float* __restrict__ bq, const float* __restrict__ bk,
                        const float* __restrict__ bv, const int* __restrict__ mask,
                        float* __restrict__ bc, float* __restrict__ mbias,
                        u32* __restrict__ tmask) {
  int t = blockIdx.x * 256 + threadIdx.x;
  if (t < 1024) bc[t] = bq[t];
  else if (t < 2048) bc[t] = bk[t - 1024];
  else if (t < 4096) bc[t] = bv[t - 2048];
  else if (t < 8192) { int i = t - 4096; mbias[i] = mask[i] ? 0.f : -1e38f; }
  else if (t < 8256) {
    // one wave (block 32, lanes 0..63): per-(b,tile64) "any masked" bitmap
    int tt = t - 8192;              // 0..63 ; b = tt>>5, tile = tt&31
    const int* mp = mask + (tt >> 5) * S_ + (tt & 31) * 64;
    int any0 = 0;
    for (int i = 0; i < 64; i++) any0 |= (mp[i] == 0);
    unsigned long long bal = __ballot(any0);
    if (tt == 0) { tmask[0] = (u32)bal; tmask[1] = (u32)(bal >> 32); }
  }
}

// transpose [R][C] f32 -> [C][R] bf16, one matrix per blockIdx.z
__global__ void k_tr_f2b(const float* __restrict__ in, u16* __restrict__ out, int R, int C) {
  __shared__ float t[32][33];
  const float* src = in + (size_t)blockIdx.z * R * C;
  u16* dst = out + (size_t)blockIdx.z * C * R;
  int r0 = blockIdx.y * 32, c0 = blockIdx.x * 32;
  for (int i = threadIdx.y; i < 32; i += 8)
    t[i][threadIdx.x] = src[(size_t)(r0 + i) * C + c0 + threadIdx.x];
  __syncthreads();
  for (int i = threadIdx.y; i < 32; i += 8)
    dst[(size_t)(c0 + i) * R + r0 + threadIdx.x] = f2bf(t[threadIdx.x][i]);
}

// ---------------- GEMM 128x128: C[m][n] = sum_k A[m][k]*Bt[n][k] ----------------
// MODE 0: QK projection epilogue (n<1024 -> Q, else K), bias per column
// MODE 2: Vt projection epilogue (A=WvT rows m=h*128+d, n=token), bias per ROW
template<int MODE>
__global__ __launch_bounds__(256)
void k_gemm(const u16* __restrict__ A, const u16* __restrict__ Bt,
            const float* __restrict__ bias, int Kdim,
            u16* __restrict__ q_out, u16* __restrict__ k_out, u16* __restrict__ vt_out) {
  const int tid = threadIdx.x;
  const int l = tid & 63, w = tid >> 6;
  const int wm = w >> 1, wn = w & 1;
  const int g = l >> 4, lo = l & 15;
  const int m0 = blockIdx.y * 128, n0 = blockIdx.x * 128;
  __shared__ u16 As[128 * 64];
  __shared__ u16 Bs[128 * 64];
  f32x4 acc[4][4] = {};
  for (int kt = 0; kt < Kdim; kt += 64) {
    __syncthreads();
    for (int cid = tid; cid < 1024; cid += 256) {
      int r = cid >> 3, c = (cid & 7) * 8;
      gload_lds16(&A[(size_t)(m0 + r) * Kdim + kt + c], &As[cid * 8]);
      gload_lds16(&Bt[(size_t)(n0 + r) * Kdim + kt + c], &Bs[cid * 8]);
    }
    __syncthreads();   // vmcnt(0) drain needed here: DMA must land
    for (int kc = 0; kc < 64; kc += 32) {
      s16x8 a[4], b[4];
      for (int i = 0; i < 4; i++)
        a[i] = *(const s16x8*)&As[(wm * 64 + i * 16 + lo) * 64 + kc + 8 * g];
      for (int i = 0; i < 4; i++)
        b[i] = *(const s16x8*)&Bs[(wn * 64 + i * 16 + lo) * 64 + kc + 8 * g];
      for (int mi = 0; mi < 4; mi++)
        for (int ni = 0; ni < 4; ni++)
          acc[mi][ni] = __builtin_amdgcn_mfma_f32_16x16x32_bf16(a[mi], b[ni], acc[mi][ni], 0, 0, 0);
    }
  }
  for (int mi = 0; mi < 4; mi++)
    for (int ni = 0; ni < 4; ni++)
      for (int j = 0; j < 4; j++) {
        int m = m0 + wm * 64 + mi * 16 + g * 4 + j;
        int n = n0 + wn * 64 + ni * 16 + lo;
        if (MODE == 0) {
          float v = acc[mi][ni][j] + bias[n];
          int bb = m >> 11, s = m & 2047;
          if (n < 1024) {
            int h = n >> 6, d = n & 63;
            q_out[(((size_t)h * B_ + bb) * S_ + s) * 64 + d] = f2bf(v);
          } else {
            int nn = n - 1024; int h = nn >> 6, d = nn & 63;
            k_out[(((size_t)h * B_ + bb) * S_ + s) * 64 + d] = f2bf(v);
          }
        } else {
          float v = acc[mi][ni][j] + bias[m];      // bias per row (bv[h*128+d])
          int h = m >> 7, d = m & 127;
          int bb = n >> 11, s = n & 2047;
          vt_out[(((size_t)h * B_ + bb) * 128 + d) * S_ + s] = f2bf(v);
        }
      }
}

// ---------------- GEMM 64x128 (res): more blocks for occupancy ----------------
__global__ __launch_bounds__(256)
void k_gemm64(const u16* __restrict__ A, const u16* __restrict__ Bt,
              const float* __restrict__ bias, int Kdim, float* __restrict__ res_out) {
  const int tid = threadIdx.x;
  const int l = tid & 63, w = tid >> 6;
  const int wm = w >> 1, wn = w & 1;
  const int g = l >> 4, lo = l & 15;
  const int m0 = blockIdx.y * 64, n0 = blockIdx.x * 128;
  __shared__ u16 As[64 * 64];
  __shared__ u16 Bs[128 * 64];
  f32x4 acc[2][4] = {};
  for (int kt = 0; kt < Kdim; kt += 64) {
    __syncthreads();
    for (int cid = tid; cid < 512; cid += 256) {
      int r = cid >> 3, c = (cid & 7) * 8;
      gload_lds16(&A[(size_t)(m0 + r) * Kdim + kt + c], &As[cid * 8]);
    }
    for (int cid = tid; cid < 1024; cid += 256) {
      int r = cid >> 3, c = (cid & 7) * 8;
      gload_lds16(&Bt[(size_t)(n0 + r) * Kdim + kt + c], &Bs[cid * 8]);
    }
    __syncthreads();
    for (int kc = 0; kc < 64; kc += 32) {
      s16x8 a[2], b[4];
      for (int i = 0; i < 2; i++)
        a[i] = *(const s16x8*)&As[(wm * 32 + i * 16 + lo) * 64 + kc + 8 * g];
      for (int i = 0; i < 4; i++)
        b[i] = *(const s16x8*)&Bs[(wn * 64 + i * 16 + lo) * 64 + kc + 8 * g];
      for (int mi = 0; mi < 2; mi++)
        for (int ni = 0; ni < 4; ni++)
          acc[mi][ni] = __builtin_amdgcn_mfma_f32_16x16x32_bf16(a[mi], b[ni], acc[mi][ni], 0, 0, 0);
    }
  }
  for (int mi = 0; mi < 2; mi++)
    for (int ni = 0; ni < 4; ni++)
      for (int j = 0; j < 4; j++) {
        int m = m0 + wm * 32 + mi * 16 + g * 4 + j;
        int n = n0 + wn * 64 + ni * 16 + lo;
        res_out[(size_t)m * 1024 + n] = acc[mi][ni][j] + bias[n];
      }
}

// ---------------- softmax denominator (pass 1 extracted) ----------------
// grid 2048: split-K halves (1024 keys each) x 64-query stripes x 32 hb.
// LDS only 18.4 KB (double-buffered K), target 6 blocks/CU = 24 waves/CU.
__global__ __launch_bounds__(256, 6)
void k_den(const u16* __restrict__ Qb, const u16* __restrict__ Kb,
           const float* __restrict__ mbias, const u32* __restrict__ tmask,
           float* __restrict__ den) {
  const int tid = threadIdx.x, l = tid & 63, w = tid >> 6;
  const int g = l >> 4, lo = l & 15;
  const int bid = blockIdx.x;
  const int xcd = bid & 7, idx = bid >> 3;          // idx in 0..255
  const int hb = xcd * 4 + (idx >> 6);              // 4 hb per XCD
  const int rem = idx & 63;
  const int s0 = (rem >> 1) * 64;
  const int half = rem & 1;
  const int b = hb & 1;
  const float scale2 = 0.03125f * 1.44269504f;
  const u32 tm = tmask[b];

  __shared__ __align__(16) u16 Ks[2][64 * 72];      // 18.4 KB

  const u16* Qhb = Qb + (size_t)hb * S_ * 64;
  const u16* Khb = Kb + (size_t)hb * S_ * 64 + (size_t)half * 1024 * 64;
  const float* mb = mbias + (size_t)b * S_ + half * 1024;

  const int q = s0 + w * 16 + lo;
  const s16x8 q0 = *(const s16x8*)&Qhb[(size_t)q * 64 + 8 * g];
  const s16x8 q1 = *(const s16x8*)&Qhb[(size_t)q * 64 + 32 + 8 * g];

  const int kr = tid >> 3, kc8 = (tid & 7) * 8;

  // stage tile 0
  {
    *(u32x4*)&Ks[0][kr * 72 + kc8] = *(const u32x4*)&Khb[(size_t)kr * 64 + kc8];
    int cid = tid + 256; int r = cid >> 3, c = (cid & 7) * 8;
    *(u32x4*)&Ks[0][r * 72 + c] = *(const u32x4*)&Khb[(size_t)r * 64 + c];
  }
  __syncthreads();
  f32x4 psv = {};
  for (int t = 0; t < 16; t++) {
    const int buf = t & 1;
    const int kt = t * 64;
    const bool pre = (t < 15);
    const bool mskt = (tm >> (half * 16 + t)) & 1;
    u32x4 kreg0, kreg1;
    if (pre) {
      const int ktn = kt + 64;
      kreg0 = *(const u32x4*)&Khb[(size_t)(ktn + kr) * 64 + kc8];
      kreg1 = *(const u32x4*)&Khb[(size_t)(ktn + kr + 32) * 64 + kc8];
    }
#pragma unroll
    for (int nf = 0; nf < 4; nf++) {
      s16x8 k0 = *(const s16x8*)&Ks[buf][(nf * 16 + lo) * 72 + 8 * g];
      s16x8 k1 = *(const s16x8*)&Ks[buf][(nf * 16 + lo) * 72 + 32 + 8 * g];
      f32x4 z = {};
      z = __builtin_amdgcn_mfma_f32_16x16x32_bf16(k0, q0, z, 0, 0, 0);
      z = __builtin_amdgcn_mfma_f32_16x16x32_bf16(k1, q1, z, 0, 0, 0);
      f32x4 m4 = {};
      if (mskt) m4 = *(const f32x4*)&mb[kt + nf * 16 + g * 4];
      psv[0] += __builtin_exp2f(z[0] * scale2 + m4[0]);
      psv[1] += __builtin_exp2f(z[1] * scale2 + m4[1]);
      psv[2] += __builtin_exp2f(z[2] * scale2 + m4[2]);
      psv[3] += __builtin_exp2f(z[3] * scale2 + m4[3]);
    }
    if (pre) {
      *(u32x4*)&Ks[buf ^ 1][kr * 72 + kc8] = kreg0;
      *(u32x4*)&Ks[buf ^ 1][(kr + 32) * 72 + kc8] = kreg1;
    }
    lds_barrier();
  }
  float ps = (psv[0] + psv[1]) + (psv[2] + psv[3]);
  ps += __shfl_xor(ps, 16, 64);
  ps += __shfl_xor(ps, 32, 64);
  if (g == 0) den[(size_t)half * 32 * S_ + (size_t)hb * S_ + q] = ps;
}

// ---------------- fused attention v9 (single pass) ----------------
// Round-7 pass-2 structure; denominator read from k_den output.
__global__ __launch_bounds__(256, 4)
void k_attn(const u16* __restrict__ Qb, const u16* __restrict__ Kb,
            const u16* __restrict__ Vtb, const float* __restrict__ mbias,
            const u32* __restrict__ tmask, const float* __restrict__ den,
            const float* __restrict__ lam_p, const float* __restrict__ ln_g,
            const float* __restrict__ ln_b, float* __restrict__ A_out,
            u16* __restrict__ cat) {
  const int tid = threadIdx.x, l = tid & 63, w = tid >> 6;
  const int g = l >> 4, lo = l & 15;
  const int bid = blockIdx.x;
  const int xcd = bid & 7, idx = bid >> 3;          // idx in 0..127
  const int hb = xcd * 4 + (idx >> 5);              // 4 hb per XCD -> 3MB K/V in L2
  const int s0 = (idx & 31) * 64;
  const int b = hb & 1, h = hb >> 1;
  const float scale2 = 0.03125f * 1.44269504f;      // (1/sqrt(1024)) * log2(e)
  const float pfac = 1.0f - lam_p[0];
  const u32 tm = tmask[b];

  __shared__ __align__(16) u16 Ks[64 * 72];         // 9.2 KB
  __shared__ __align__(16) u16 Vs[128 * 72];        // 18.4 KB
  __shared__ __align__(16) u16 Ps[4][16 * 72];      // 9.2 KB   total 36.8 KB -> 4 blocks/CU

  const u16* Qhb = Qb + (size_t)hb * S_ * 64;
  const u16* Khb = Kb + (size_t)hb * S_ * 64;
  const u16* Vthb = Vtb + (size_t)hb * 128 * S_;
  const float* mb = mbias + (size_t)b * S_;

  // Q fragment: query q = s0 + w*16 + lo
  const int q = s0 + w * 16 + lo;
  const s16x8 q0 = *(const s16x8*)&Qhb[(size_t)q * 64 + 8 * g];
  const s16x8 q1 = *(const s16x8*)&Qhb[(size_t)q * 64 + 32 + 8 * g];
  float* Arow = A_out + ((size_t)hb * S_ + q) * S_;

  const float d0 = den[(size_t)hb * S_ + q];
  const float d1 = den[(size_t)32 * S_ + (size_t)hb * S_ + q];
  const float rinv = pfac / (d0 + d1);

  // staging geometry: K tile = 512 chunks of 16B (2/thread), V tile = 1024 (4/thread)
  const int kr = tid >> 3, kc8 = (tid & 7) * 8;

  // prologue: stage K tile 0 + V tile 0
  {
    *(u32x4*)&Ks[kr * 72 + kc8] = *(const u32x4*)&Khb[(size_t)kr * 64 + kc8];
    int cid = tid + 256; int r = cid >> 3, c = (cid & 7) * 8;
    *(u32x4*)&Ks[r * 72 + c] = *(const u32x4*)&Khb[(size_t)r * 64 + c];
  }
#pragma unroll
  for (int i = 0; i < 4; i++) {
    int cid = tid + i * 256;
    int r = cid >> 3, c = (cid & 7) * 8;
    *(u32x4*)&Vs[r * 72 + c] = *(const u32x4*)&Vthb[(size_t)r * S_ + c];
  }
  __syncthreads();

  // main loop: recompute scores, write A (NT f32x4), accumulate O = A*V
  f32x4 o[8] = {};
  for (int t = 0; t < 32; t++) {
    const int kt = t * 64;
    const bool pre = (t < 31);
    const bool mskt = (tm >> t) & 1;
    u32x4 kreg0, kreg1, vreg[4];
    if (pre) {   // issue loads for tile t+1 BEFORE this tile's NT stores
      const int ktn = kt + 64;
      kreg0 = *(const u32x4*)&Khb[(size_t)(ktn + kr) * 64 + kc8];
      kreg1 = *(const u32x4*)&Khb[(size_t)(ktn + kr + 32) * 64 + kc8];
#pragma unroll
      for (int i = 0; i < 4; i++) {
        int cid = tid + i * 256;
        vreg[i] = *(const u32x4*)&Vthb[(size_t)(cid >> 3) * S_ + ktn + (cid & 7) * 8];
      }
    }
    // QK reads + MFMA
    f32x4 z[4];
#pragma unroll
    for (int nf = 0; nf < 4; nf++) {
      s16x8 k0 = *(const s16x8*)&Ks[(nf * 16 + lo) * 72 + 8 * g];
      s16x8 k1 = *(const s16x8*)&Ks[(nf * 16 + lo) * 72 + 32 + 8 * g];
      f32x4 zz = {};
      zz = __builtin_amdgcn_mfma_f32_16x16x32_bf16(k0, q0, zz, 0, 0, 0);
      z[nf] = __builtin_amdgcn_mfma_f32_16x16x32_bf16(k1, q1, zz, 0, 0, 0);
    }
    // softmax + A-store + P staging
#pragma unroll
    for (int nf = 0; nf < 4; nf++) {
      f32x4 m4 = {};
      if (mskt) m4 = *(const f32x4*)&mb[kt + nf * 16 + g * 4];
      f32x4 p4;
      p4[0] = __builtin_exp2f(z[nf][0] * scale2 + m4[0]) * rinv;
      p4[1] = __builtin_exp2f(z[nf][1] * scale2 + m4[1]) * rinv;
      p4[2] = __builtin_exp2f(z[nf][2] * scale2 + m4[2]) * rinv;
      p4[3] = __builtin_exp2f(z[nf][3] * scale2 + m4[3]) * rinv;
      __builtin_nontemporal_store(p4, (f32x4*)&Arow[kt + nf * 16 + g * 4]);
      u16x4 pb;
      pb[0] = f2bf(p4[0]); pb[1] = f2bf(p4[1]);
      pb[2] = f2bf(p4[2]); pb[3] = f2bf(p4[3]);
      *(u16x4*)&Ps[w][lo * 72 + nf * 16 + g * 4] = pb;
    }
    // PV (Ps wave-private; Vs stable until barA)
#pragma unroll
    for (int kc = 0; kc < 2; kc++) {
      s16x8 pa = *(const s16x8*)&Ps[w][lo * 72 + kc * 32 + 8 * g];
#pragma unroll
      for (int vf = 0; vf < 8; vf++) {
        s16x8 bv = *(const s16x8*)&Vs[(vf * 16 + lo) * 72 + kc * 32 + 8 * g];
        o[vf] = __builtin_amdgcn_mfma_f32_16x16x32_bf16(pa, bv, o[vf], 0, 0, 0);
      }
    }
    lds_barrier();   // barA: all waves' Ks/Vs reads done; stores stay in flight
    if (pre) {       // refill: load-wait targets L(t+1), issued before S(t)
      *(u32x4*)&Ks[kr * 72 + kc8] = kreg0;
      *(u32x4*)&Ks[(kr + 32) * 72 + kc8] = kreg1;
#pragma unroll
      for (int i = 0; i < 4; i++) {
        int cid = tid + i * 256;
        *(u32x4*)&Vs[(cid >> 3) * 72 + (cid & 7) * 8] = vreg[i];
      }
    }
    lds_barrier();   // barB: refills visible to all waves for next tile
  }

  // ---- LayerNorm(128) * 0.2 epilogue -> cat[b][s][h*128 + c] ----
#pragma unroll
  for (int j = 0; j < 4; j++) {
    float sum = 0.f, sq = 0.f;
#pragma unroll
    for (int vf = 0; vf < 8; vf++) { float xv = o[vf][j]; sum += xv; sq += xv * xv; }
    for (int msk = 1; msk < 16; msk <<= 1) {
      sum += __shfl_xor(sum, msk, 64);
      sq += __shfl_xor(sq, msk, 64);
    }
    float mean = sum * (1.f / 128.f);
    float var = sq * (1.f / 128.f) - mean * mean;
    float rstd = rsqrtf(var + 1e-5f);
    int s = s0 + w * 16 + g * 4 + j;
    u16* cp = cat + ((size_t)(b * S_ + s)) * 2048 + h * 128;
#pragma unroll
    for (int vf = 0; vf < 8; vf++) {
      int c = vf * 16 + lo;
      float y = (o[vf][j] - mean) * rstd * ln_g[c] + ln_b[c];
      cp[c] = f2bf(y * 0.2f);
    }
  }
}

// ---------------- launcher ----------------

extern "C" void kernel_launch(void* const* d_in, const int* in_sizes, int n_in,
                              void* d_out, int out_size, void* d_ws, size_t ws_size,
                              hipStream_t stream) {
  const float* x    = (const float*)d_in[0];
  const float* lam  = (const float*)d_in[1];
  const int*   mask = (const int*)d_in[2];
  const float* wq   = (const float*)d_in[3];
  const float* bq   = (const float*)d_in[4];
  const float* wk   = (const float*)d_in[5];
  const float* bk   = (const float*)d_in[6];
  const float* wv   = (const float*)d_in[7];
  const float* bv   = (const float*)d_in[8];
  const float* wo   = (const float*)d_in[9];
  const float* bo   = (const float*)d_in[10];
  const float* lng  = (const float*)d_in[11];
  const float* lnb  = (const float*)d_in[12];

  float* res = (float*)d_out;
  float* A   = res + (size_t)NTOK * DM;

  char* ws = (char*)d_ws;
  size_t off = 0;
  auto alloc = [&](size_t bytes) {
    void* p = ws + off;
    off += (bytes + 255) & ~(size_t)255;
    return p;
  };
  u16*   xb    = (u16*)  alloc((size_t)NTOK * DM * 2);       // dead after gemms
  u16*   Wct   = (u16*)  alloc((size_t)4096 * 1024 * 2);     // dead after gemms
  float* bc    = (float*)alloc(4096 * 4);
  float* mbias = (float*)alloc(4096 * 4);
  u32*   tmask = (u32*)  alloc(2 * 4);
  float* den   = (float*)alloc((size_t)2 * 32 * S_ * 4);     // 512 KB
  u16*   wot   = (u16*)  alloc((size_t)1024 * 2048 * 2);
  u16*   Qb    = (u16*)  alloc((size_t)32 * S_ * 64 * 2);
  u16*   Kb2   = (u16*)  alloc((size_t)32 * S_ * 64 * 2);
  u16*   Vtb   = (u16*)  alloc((size_t)32 * S_ * 128 * 2);
  u16*   catb  = (u16*)ws;  // reuse xb+Wct region (16 MB), both dead by k_attn

  k_cvt_x<<<4096, 256, 0, stream>>>(x, xb);
  k_small<<<33, 256, 0, stream>>>(bq, bk, bv, mask, bc, mbias, tmask);
  k_tr_f2b<<<dim3(2, 32, 16), dim3(32, 8), 0, stream>>>(wq, Wct, 1024, 64);
  k_tr_f2b<<<dim3(2, 32, 16), dim3(32, 8), 0, stream>>>(wk, Wct + 1024 * 1024, 1024, 64);
  k_tr_f2b<<<dim3(4, 32, 16), dim3(32, 8), 0, stream>>>(wv, Wct + 2048 * 1024, 1024, 128);
  k_tr_f2b<<<dim3(32, 64, 1), dim3(32, 8), 0, stream>>>(wo, wot, 2048, 1024);
  // gemm1a: Q,K  (M=4096 tokens, N=2048)
  k_gemm<0><<<dim3(16, 32), 256, 0, stream>>>(xb, Wct, bc, 1024, Qb, Kb2, nullptr);
  // gemm1b: Vt directly (M=2048 v-features, N=4096 tokens)
  k_gemm<2><<<dim3(32, 16), 256, 0, stream>>>(Wct + (size_t)2048 * 1024, xb, bc + 2048,
                                              1024, nullptr, nullptr, Vtb);
  // softmax denominators (split-K halves, high occupancy)
  k_den<<<dim3(2048), 256, 0, stream>>>(Qb, Kb2, mbias, tmask, den);
  // single-pass attention
  k_attn<<<dim3(1024), 256, 0, stream>>>(Qb, Kb2, Vtb, mbias, tmask, den, lam, lng, lnb, A, catb);
  // gemm3: res (M=4096, N=1024, K=2048), 64-row tiles -> 512 blocks
  k_gemm64<<<dim3(8, 64), 256, 0, stream>>>(catb, wot, bo, 2048, res);
}

// Round 10
// 347.679 us; speedup vs baseline: 1.1346x; 1.1346x over previous
//
#include <hip/hip_runtime.h>
#include <hip/hip_bf16.h>

#define DM   1024
#define DI   64
#define H_   16
#define B_   2
#define S_   2048
#define NTOK 4096   // B*S

typedef unsigned short u16;
typedef unsigned int u32;
typedef __attribute__((ext_vector_type(8))) short s16x8;
typedef __attribute__((ext_vector_type(4))) float f32x4;
typedef __attribute__((ext_vector_type(4))) unsigned int u32x4;
typedef __attribute__((ext_vector_type(4))) unsigned short u16x4;

#define AS1 __attribute__((address_space(1)))
#define AS3 __attribute__((address_space(3)))

static __device__ __forceinline__ u16 f2bf(float f) {
  unsigned int u = __builtin_bit_cast(unsigned int, f);
  unsigned int r = (u + 0x7fffu + ((u >> 16) & 1u)) >> 16;
  return (u16)r;
}

static __device__ __forceinline__ void gload_lds16(const u16* g, u16* l) {
  __builtin_amdgcn_global_load_lds((const AS1 u32*)(const void*)g,
                                   (AS3 u32*)(void*)l, 16, 0, 0);
}

// LDS-only barrier: drain this wave's DS ops, then s_barrier. Global NT stores
// and prefetch loads stay in flight (no vmcnt(0) drain like __syncthreads).
static __device__ __forceinline__ void lds_barrier() {
  asm volatile("s_waitcnt lgkmcnt(0)\n\ts_barrier" ::: "memory");
}

// ---------------- small prep kernels ----------------

__global__ void k_cvt_x(const float* __restrict__ in, u16* __restrict__ out) {
  int i = (blockIdx.x * 256 + threadIdx.x) * 4;
  float4 v = *(const float4*)&in[i];
  u16x4 o;
  o[0] = f2bf(v.x); o[1] = f2bf(v.y); o[2] = f2bf(v.z); o[3] = f2bf(v.w);
  *(u16x4*)&out[i] = o;
}

__global__ void k_small(const float* __restrict__ bq, const float* __restrict__ bk,
                        const float* __restrict__ bv, const int* __restrict__ mask,
                        float* __restrict__ bc, float* __restrict__ mbias) {
  int t = blockIdx.x * 256 + threadIdx.x;
  if (t < 1024) bc[t] = bq[t];
  else if (t < 2048) bc[t] = bk[t - 1024];
  else if (t < 4096) bc[t] = bv[t - 2048];
  else if (t < 8192) { int i = t - 4096; mbias[i] = mask[i] ? 0.f : -1e38f; }
}

// transpose [R][C] f32 -> [C][R] bf16, one matrix per blockIdx.z
__global__ void k_tr_f2b(const float* __restrict__ in, u16* __restrict__ out, int R, int C) {
  __shared__ float t[32][33];
  const float* src = in + (size_t)blockIdx.z * R * C;
  u16* dst = out + (size_t)blockIdx.z * C * R;
  int r0 = blockIdx.y * 32, c0 = blockIdx.x * 32;
  for (int i = threadIdx.y; i < 32; i += 8)
    t[i][threadIdx.x] = src[(size_t)(r0 + i) * C + c0 + threadIdx.x];
  __syncthreads();
  for (int i = threadIdx.y; i < 32; i += 8)
    dst[(size_t)(c0 + i) * R + r0 + threadIdx.x] = f2bf(t[threadIdx.x][i]);
}

// transpose [R][C] bf16 -> [C][R] bf16, one matrix per blockIdx.z
__global__ void k_tr_b2b(const u16* __restrict__ in, u16* __restrict__ out, int R, int C) {
  __shared__ u16 t[32][33];
  const u16* src = in + (size_t)blockIdx.z * R * C;
  u16* dst = out + (size_t)blockIdx.z * C * R;
  int r0 = blockIdx.y * 32, c0 = blockIdx.x * 32;
  for (int i = threadIdx.y; i < 32; i += 8)
    t[i][threadIdx.x] = src[(size_t)(r0 + i) * C + c0 + threadIdx.x];
  __syncthreads();
  for (int i = threadIdx.y; i < 32; i += 8)
    dst[(size_t)(c0 + i) * R + r0 + threadIdx.x] = t[threadIdx.x][i];
}

// ---------------- GEMM 128x128: QKV projection (MODE 0) ----------------
template<int MODE>
__global__ __launch_bounds__(256)
void k_gemm(const u16* __restrict__ A, const u16* __restrict__ Bt,
            const float* __restrict__ bias, int Kdim,
            u16* __restrict__ q_out, u16* __restrict__ k_out, u16* __restrict__ v_out,
            float* __restrict__ res_out) {
  const int tid = threadIdx.x;
  const int l = tid & 63, w = tid >> 6;
  const int wm = w >> 1, wn = w & 1;
  const int g = l >> 4, lo = l & 15;
  const int m0 = blockIdx.y * 128, n0 = blockIdx.x * 128;
  __shared__ u16 As[128 * 64];
  __shared__ u16 Bs[128 * 64];
  f32x4 acc[4][4] = {};
  for (int kt = 0; kt < Kdim; kt += 64) {
    __syncthreads();
    for (int cid = tid; cid < 1024; cid += 256) {
      int r = cid >> 3, c = (cid & 7) * 8;
      gload_lds16(&A[(size_t)(m0 + r) * Kdim + kt + c], &As[cid * 8]);
      gload_lds16(&Bt[(size_t)(n0 + r) * Kdim + kt + c], &Bs[cid * 8]);
    }
    __syncthreads();   // vmcnt(0) drain needed here: DMA must land
    for (int kc = 0; kc < 64; kc += 32) {
      s16x8 a[4], b[4];
      for (int i = 0; i < 4; i++)
        a[i] = *(const s16x8*)&As[(wm * 64 + i * 16 + lo) * 64 + kc + 8 * g];
      for (int i = 0; i < 4; i++)
        b[i] = *(const s16x8*)&Bs[(wn * 64 + i * 16 + lo) * 64 + kc + 8 * g];
      for (int mi = 0; mi < 4; mi++)
        for (int ni = 0; ni < 4; ni++)
          acc[mi][ni] = __builtin_amdgcn_mfma_f32_16x16x32_bf16(a[mi], b[ni], acc[mi][ni], 0, 0, 0);
    }
  }
  for (int mi = 0; mi < 4; mi++)
    for (int ni = 0; ni < 4; ni++)
      for (int j = 0; j < 4; j++) {
        int m = m0 + wm * 64 + mi * 16 + g * 4 + j;
        int n = n0 + wn * 64 + ni * 16 + lo;
        float v = acc[mi][ni][j] + bias[n];
        if (MODE == 0) {
          int bb = m >> 11, s = m & 2047;
          if (n < 1024) {
            int h = n >> 6, d = n & 63;
            q_out[(((size_t)h * B_ + bb) * S_ + s) * 64 + d] = f2bf(v);
          } else if (n < 2048) {
            int nn = n - 1024; int h = nn >> 6, d = nn & 63;
            k_out[(((size_t)h * B_ + bb) * S_ + s) * 64 + d] = f2bf(v);
          } else {
            int nn = n - 2048; int h = nn >> 7, d = nn & 127;
            v_out[(((size_t)h * B_ + bb) * S_ + s) * 128 + d] = f2bf(v);
          }
        } else {
          res_out[(size_t)m * 1024 + n] = v;
        }
      }
}

// ---------------- GEMM 64x128 (res): 512 blocks -> 2 blocks/CU ----------------
__global__ __launch_bounds__(256)
void k_gemm64(const u16* __restrict__ A, const u16* __restrict__ Bt,
              const float* __restrict__ bias, int Kdim, float* __restrict__ res_out) {
  const int tid = threadIdx.x;
  const int l = tid & 63, w = tid >> 6;
  const int wm = w >> 1, wn = w & 1;
  const int g = l >> 4, lo = l & 15;
  const int m0 = blockIdx.y * 64, n0 = blockIdx.x * 128;
  __shared__ u16 As[64 * 64];
  __shared__ u16 Bs[128 * 64];
  f32x4 acc[2][4] = {};
  for (int kt = 0; kt < Kdim; kt += 64) {
    __syncthreads();
    for (int cid = tid; cid < 512; cid += 256) {
      int r = cid >> 3, c = (cid & 7) * 8;
      gload_lds16(&A[(size_t)(m0 + r) * Kdim + kt + c], &As[cid * 8]);
    }
    for (int cid = tid; cid < 1024; cid += 256) {
      int r = cid >> 3, c = (cid & 7) * 8;
      gload_lds16(&Bt[(size_t)(n0 + r) * Kdim + kt + c], &Bs[cid * 8]);
    }
    __syncthreads();
    for (int kc = 0; kc < 64; kc += 32) {
      s16x8 a[2], b[4];
      for (int i = 0; i < 2; i++)
        a[i] = *(const s16x8*)&As[(wm * 32 + i * 16 + lo) * 64 + kc + 8 * g];
      for (int i = 0; i < 4; i++)
        b[i] = *(const s16x8*)&Bs[(wn * 64 + i * 16 + lo) * 64 + kc + 8 * g];
      for (int mi = 0; mi < 2; mi++)
        for (int ni = 0; ni < 4; ni++)
          acc[mi][ni] = __builtin_amdgcn_mfma_f32_16x16x32_bf16(a[mi], b[ni], acc[mi][ni], 0, 0, 0);
    }
  }
  for (int mi = 0; mi < 2; mi++)
    for (int ni = 0; ni < 4; ni++)
      for (int j = 0; j < 4; j++) {
        int m = m0 + wm * 32 + mi * 16 + g * 4 + j;
        int n = n0 + wn * 64 + ni * 16 + lo;
        res_out[(size_t)m * 1024 + n] = acc[mi][ni][j] + bias[n];
      }
}

// ---------------- fused attention v7 (round-7 best-known) ----------------
__global__ __launch_bounds__(256, 4)
void k_attn(const u16* __restrict__ Qb, const u16* __restrict__ Kb,
            const u16* __restrict__ Vtb, const float* __restrict__ mbias,
            const float* __restrict__ lam_p, const float* __restrict__ ln_g,
            const float* __restrict__ ln_b, float* __restrict__ A_out,
            u16* __restrict__ cat) {
  const int tid = threadIdx.x, l = tid & 63, w = tid >> 6;
  const int g = l >> 4, lo = l & 15;
  const int bid = blockIdx.x;
  const int xcd = bid & 7, idx = bid >> 3;          // idx in 0..127
  const int hb = xcd * 4 + (idx >> 5);              // 4 hb per XCD -> 3MB K/V in L2
  const int s0 = (idx & 31) * 64;
  const int b = hb & 1, h = hb >> 1;
  const float scale2 = 0.03125f * 1.44269504f;      // (1/sqrt(1024)) * log2(e)
  const float pfac = 1.0f - lam_p[0];

  __shared__ __align__(16) u16 Ks[64 * 72];         // 9.2 KB
  __shared__ __align__(16) u16 Vs[128 * 72];        // 18.4 KB (K buf B in pass 1)
  __shared__ __align__(16) u16 Ps[4][16 * 72];      // 9.2 KB   total 36 KB -> 4 blocks/CU

  const u16* Qhb = Qb + (size_t)hb * S_ * 64;
  const u16* Khb = Kb + (size_t)hb * S_ * 64;
  const u16* Vthb = Vtb + (size_t)hb * 128 * S_;
  const float* mb = mbias + (size_t)b * S_;

  // Q fragment: query q = s0 + w*16 + lo
  const int q = s0 + w * 16 + lo;
  const s16x8 q0 = *(const s16x8*)&Qhb[(size_t)q * 64 + 8 * g];
  const s16x8 q1 = *(const s16x8*)&Qhb[(size_t)q * 64 + 32 + 8 * g];
  float* Arow = A_out + ((size_t)hb * S_ + q) * S_;

  // staging geometry: K tile = 512 chunks of 16B (2/thread), V tile = 1024 (4/thread)
  const int kr = tid >> 3, kc8 = (tid & 7) * 8;

  // ---- pass 1: per-lane sum of exp2(scale2*z + mb); K ping-pong Ks <-> Vs ----
  {
    *(u32x4*)&Ks[kr * 72 + kc8] = *(const u32x4*)&Khb[(size_t)kr * 64 + kc8];
    int cid = tid + 256; int r = cid >> 3, c = (cid & 7) * 8;
    *(u32x4*)&Ks[r * 72 + c] = *(const u32x4*)&Khb[(size_t)r * 64 + c];
  }
  __syncthreads();
  f32x4 psv = {};
  for (int t = 0; t < 32; t++) {
    const u16* rbuf = (t & 1) ? Vs : Ks;
    u16* wbuf = (t & 1) ? Ks : Vs;
    const int kt = t * 64;
    const int ktn = (kt + 64) & (S_ - 1);           // wraps: t=31 restages tile 0 -> Ks
    u32x4 kreg0 = *(const u32x4*)&Khb[(size_t)(ktn + kr) * 64 + kc8];
    u32x4 kreg1 = *(const u32x4*)&Khb[(size_t)(ktn + kr + 32) * 64 + kc8];
#pragma unroll
    for (int nf = 0; nf < 4; nf++) {
      s16x8 k0 = *(const s16x8*)&rbuf[(nf * 16 + lo) * 72 + 8 * g];
      s16x8 k1 = *(const s16x8*)&rbuf[(nf * 16 + lo) * 72 + 32 + 8 * g];
      f32x4 z = {};
      z = __builtin_amdgcn_mfma_f32_16x16x32_bf16(k0, q0, z, 0, 0, 0);
      z = __builtin_amdgcn_mfma_f32_16x16x32_bf16(k1, q1, z, 0, 0, 0);
      f32x4 m4 = *(const f32x4*)&mb[kt + nf * 16 + g * 4];
      psv[0] += __builtin_exp2f(z[0] * scale2 + m4[0]);
      psv[1] += __builtin_exp2f(z[1] * scale2 + m4[1]);
      psv[2] += __builtin_exp2f(z[2] * scale2 + m4[2]);
      psv[3] += __builtin_exp2f(z[3] * scale2 + m4[3]);
    }
    *(u32x4*)&wbuf[kr * 72 + kc8] = kreg0;
    *(u32x4*)&wbuf[(kr + 32) * 72 + kc8] = kreg1;
    __syncthreads();
  }
  float ps = (psv[0] + psv[1]) + (psv[2] + psv[3]);
  ps += __shfl_xor(ps, 16, 64);
  ps += __shfl_xor(ps, 32, 64);
  const float rinv = pfac / ps;

  // ---- pass 2 prologue: Ks already holds K tile 0; stage V tile 0 ----
#pragma unroll
  for (int i = 0; i < 4; i++) {
    int cid = tid + i * 256;
    int r = cid >> 3, c = (cid & 7) * 8;
    *(u32x4*)&Vs[r * 72 + c] = *(const u32x4*)&Vthb[(size_t)r * S_ + c];
  }
  __syncthreads();

  // ---- pass 2: recompute, write A (NT f32x4), accumulate O = A*V ----
  f32x4 o[8] = {};
  for (int t = 0; t < 32; t++) {
    const int kt = t * 64;
    const bool pre = (t < 31);
    u32x4 kreg0, kreg1, vreg[4];
    if (pre) {   // issue loads for tile t+1 BEFORE this tile's NT stores
      const int ktn = kt + 64;
      kreg0 = *(const u32x4*)&Khb[(size_t)(ktn + kr) * 64 + kc8];
      kreg1 = *(const u32x4*)&Khb[(size_t)(ktn + kr + 32) * 64 + kc8];
#pragma unroll
      for (int i = 0; i < 4; i++) {
        int cid = tid + i * 256;
        vreg[i] = *(const u32x4*)&Vthb[(size_t)(cid >> 3) * S_ + ktn + (cid & 7) * 8];
      }
    }
    // QK reads + MFMA
    f32x4 z[4];
#pragma unroll
    for (int nf = 0; nf < 4; nf++) {
      s16x8 k0 = *(const s16x8*)&Ks[(nf * 16 + lo) * 72 + 8 * g];
      s16x8 k1 = *(const s16x8*)&Ks[(nf * 16 + lo) * 72 + 32 + 8 * g];
      f32x4 zz = {};
      zz = __builtin_amdgcn_mfma_f32_16x16x32_bf16(k0, q0, zz, 0, 0, 0);
      z[nf] = __builtin_amdgcn_mfma_f32_16x16x32_bf16(k1, q1, zz, 0, 0, 0);
    }
    // softmax + A-store + P staging
#pragma unroll
    for (int nf = 0; nf < 4; nf++) {
      f32x4 m4 = *(const f32x4*)&mb[kt + nf * 16 + g * 4];
      f32x4 p4;
      p4[0] = __builtin_exp2f(z[nf][0] * scale2 + m4[0]) * rinv;
      p4[1] = __builtin_exp2f(z[nf][1] * scale2 + m4[1]) * rinv;
      p4[2] = __builtin_exp2f(z[nf][2] * scale2 + m4[2]) * rinv;
      p4[3] = __builtin_exp2f(z[nf][3] * scale2 + m4[3]) * rinv;
      __builtin_nontemporal_store(p4, (f32x4*)&Arow[kt + nf * 16 + g * 4]);
      u16x4 pb;
      pb[0] = f2bf(p4[0]); pb[1] = f2bf(p4[1]);
      pb[2] = f2bf(p4[2]); pb[3] = f2bf(p4[3]);
      *(u16x4*)&Ps[w][lo * 72 + nf * 16 + g * 4] = pb;
    }
    // PV (Ps wave-private; Vs stable until barA)
#pragma unroll
    for (int kc = 0; kc < 2; kc++) {
      s16x8 pa = *(const s16x8*)&Ps[w][lo * 72 + kc * 32 + 8 * g];
#pragma unroll
      for (int vf = 0; vf < 8; vf++) {
        s16x8 bv = *(const s16x8*)&Vs[(vf * 16 + lo) * 72 + kc * 32 + 8 * g];
        o[vf] = __builtin_amdgcn_mfma_f32_16x16x32_bf16(pa, bv, o[vf], 0, 0, 0);
      }
    }
    lds_barrier();   // barA: all waves' Ks/Vs reads done; stores stay in flight
    if (pre) {       // refill: load-wait targets L(t+1), issued before S(t)
      *(u32x4*)&Ks[kr * 72 + kc8] = kreg0;
      *(u32x4*)&Ks[(kr + 32) * 72 + kc8] = kreg1;
#pragma unroll
      for (int i = 0; i < 4; i++) {
        int cid = tid + i * 256;
        *(u32x4*)&Vs[(cid >> 3) * 72 + (cid & 7) * 8] = vreg[i];
      }
    }
    lds_barrier();   // barB: refills visible to all waves for next tile
  }

  // ---- LayerNorm(128) * 0.2 epilogue -> cat[b][s][h*128 + c] ----
#pragma unroll
  for (int j = 0; j < 4; j++) {
    float sum = 0.f, sq = 0.f;
#pragma unroll
    for (int vf = 0; vf < 8; vf++) { float xv = o[vf][j]; sum += xv; sq += xv * xv; }
    for (int msk = 1; msk < 16; msk <<= 1) {
      sum += __shfl_xor(sum, msk, 64);
      sq += __shfl_xor(sq, msk, 64);
    }
    float mean = sum * (1.f / 128.f);
    float var = sq * (1.f / 128.f) - mean * mean;
    float rstd = rsqrtf(var + 1e-5f);
    int s = s0 + w * 16 + g * 4 + j;
    u16* cp = cat + ((size_t)(b * S_ + s)) * 2048 + h * 128;
#pragma unroll
    for (int vf = 0; vf < 8; vf++) {
      int c = vf * 16 + lo;
      float y = (o[vf][j] - mean) * rstd * ln_g[c] + ln_b[c];
      cp[c] = f2bf(y * 0.2f);
    }
  }
}

// ---------------- launcher ----------------

extern "C" void kernel_launch(void* const* d_in, const int* in_sizes, int n_in,
                              void* d_out, int out_size, void* d_ws, size_t ws_size,
                              hipStream_t stream) {
  const float* x    = (const float*)d_in[0];
  const float* lam  = (const float*)d_in[1];
  const int*   mask = (const int*)d_in[2];
  const float* wq   = (const float*)d_in[3];
  const float* bq   = (const float*)d_in[4];
  const float* wk   = (const float*)d_in[5];
  const float* bk   = (const float*)d_in[6];
  const float* wv   = (const float*)d_in[7];
  const float* bv   = (const float*)d_in[8];
  const float* wo   = (const float*)d_in[9];
  const float* bo   = (const float*)d_in[10];
  const float* lng  = (const float*)d_in[11];
  const float* lnb  = (const float*)d_in[12];

  float* res = (float*)d_out;
  float* A   = res + (size_t)NTOK * DM;

  char* ws = (char*)d_ws;
  size_t off = 0;
  auto alloc = [&](size_t bytes) {
    void* p = ws + off;
    off += (bytes + 255) & ~(size_t)255;
    return p;
  };
  u16*   xb    = (u16*)  alloc((size_t)NTOK * DM * 2);       // dead after gemm1
  u16*   Wct   = (u16*)  alloc((size_t)4096 * 1024 * 2);     // dead after gemm1
  float* bc    = (float*)alloc(4096 * 4);
  float* mbias = (float*)alloc(4096 * 4);
  u16*   wot   = (u16*)  alloc((size_t)1024 * 2048 * 2);
  u16*   Qb    = (u16*)  alloc((size_t)32 * S_ * 64 * 2);
  u16*   Kb2   = (u16*)  alloc((size_t)32 * S_ * 64 * 2);
  u16*   Vb    = (u16*)  alloc((size_t)32 * S_ * 128 * 2);
  u16*   Vtb   = (u16*)  alloc((size_t)32 * S_ * 128 * 2);
  u16*   catb  = (u16*)ws;  // reuse xb+Wct region (16 MB), both dead by k_attn

  k_cvt_x<<<4096, 256, 0, stream>>>(x, xb);
  k_small<<<32, 256, 0, stream>>>(bq, bk, bv, mask, bc, mbias);
  k_tr_f2b<<<dim3(2, 32, 16), dim3(32, 8), 0, stream>>>(wq, Wct, 1024, 64);
  k_tr_f2b<<<dim3(2, 32, 16), dim3(32, 8), 0, stream>>>(wk, Wct + 1024 * 1024, 1024, 64);
  k_tr_f2b<<<dim3(4, 32, 16), dim3(32, 8), 0, stream>>>(wv, Wct + 2048 * 1024, 1024, 128);
  k_tr_f2b<<<dim3(32, 64, 1), dim3(32, 8), 0, stream>>>(wo, wot, 2048, 1024);
  k_gemm<0><<<dim3(32, 32), 256, 0, stream>>>(xb, Wct, bc, 1024, Qb, Kb2, Vb, nullptr);
  k_tr_b2b<<<dim3(4, 64, 32), dim3(32, 8), 0, stream>>>(Vb, Vtb, 2048, 128);
  k_attn<<<dim3(1024), 256, 0, stream>>>(Qb, Kb2, Vtb, mbias, lam, lng, lnb, A, catb);
  // gemm3: res (M=4096, N=1024, K=2048), 64-row tiles -> 512 blocks (2/CU)
  k_gemm64<<<dim3(8, 64), 256, 0, stream>>>(catb, wot, bo, 2048, res);
}